// Round 10
// baseline (93.691 us; speedup 1.0000x reference)
//
#include <hip/hip_runtime.h>

// ComplexLinearAndLeakyReLU — round 10: W-fold. d = W(M Z) = (WM) Z, so precompute
// WM = W@M once and compute Y and D from the SAME Zt LDS tile in one K=768 loop.
// Removes Y-staging, GEMM2, W loads, and 2 of 3 barriers. Basis per round 9.

constexpr float EPSf  = 1e-6f;
constexpr int Bdim = 8, Cdim = 2048, Edim = 256, Fdim = 256;
constexpr int NT  = 16;
constexpr int KC1 = 24;          // K=768 in chunks of 32
constexpr int KC2 = 8;           // (r9 fallback) K=256
constexpr int ZLD = 776;         // Zt row stride in halves (768 + 8 pad)
constexpr int YLD = 264;         // (r9 fallback) Yt row stride
constexpr int M_ROWS = KC1 * 16 * 64;   // 24576 fragment rows
constexpr int W_ROWS = KC2 * 16 * 64;   // 8192 fragment rows

typedef __attribute__((ext_vector_type(8))) _Float16 half8;
typedef __attribute__((ext_vector_type(4))) _Float16 half4;
typedef __attribute__((ext_vector_type(4))) float    f32x4;

// ---- basis + abc via orthonormal-column identity (round 9, validated) ----
__device__ __forceinline__ void basis_abc(float Xx, float Xy, float Xz,
                                          float Jx, float Jy, float Jz,
                                          float* a, float* bb, float* cc)
{
    const float jn  = sqrtf(Jx*Jx + Jy*Jy + Jz*Jz) + EPSf;
    const float rj  = __builtin_amdgcn_rcpf(jn);
    const float nJz = Jz * rj;
    const float h   = (Jx*Jx + Jy*Jy) * (rj * rj);
    const float Uz  = -h * __builtin_amdgcn_rcpf(nJz + EPSf);
    const float un  = sqrtf(h + Uz*Uz) + EPSf;
    const float mx  = Uz * __builtin_amdgcn_rcpf(un);
    const float mz  = nJz;
    const float t   = mx*Xx + mz*Xz;
    a[0]  = Xx - mx*t;   a[1]  = Xy;            a[2]  = Xz - mz*t;
    bb[0] = mz*Xy;       bb[1] = mx*Xz - mz*Xx; bb[2] = -(mx*Xy);
    cc[0] = mx*t;        cc[1] = 0.f;           cc[2] = mz*t;
}

// ---------------- prep 1: fp32 -> fp16 fragments of M=[A|Bw|Cw] and W ----------------
__global__ __launch_bounds__(256)
void prep_weights_f16(const float* __restrict__ Ap, const float* __restrict__ Bp,
                      const float* __restrict__ Cp, const float* __restrict__ Wp,
                      _Float16* __restrict__ ws)
{
    const int tid = blockIdx.x * 256 + threadIdx.x;
    const bool isW = tid >= M_ROWS;
    const int row = isW ? tid - M_ROWS : tid;
    const int l   = row & 63;
    const int ft  = (row >> 6) & 15;
    const int kc  = row >> 10;
    const int f   = ft * 16 + (l & 15);
    const int k0  = kc * 32 + ((l >> 4) << 3);

    const float* src;
    int e0;
    if (isW)            { src = Wp; e0 = k0; }
    else if (k0 < 256)  { src = Ap; e0 = k0; }
    else if (k0 < 512)  { src = Bp; e0 = k0 - 256; }
    else                { src = Cp; e0 = k0 - 512; }

    const float* p = src + f * 256 + e0;
    half8 v;
    #pragma unroll
    for (int j = 0; j < 8; ++j) v[j] = (_Float16)p[j];

    _Float16* dst = ws + (isW ? (size_t)M_ROWS * 8 : 0);
    *reinterpret_cast<half8*>(dst + (size_t)row * 8) = v;
}

// ---------------- prep 2: WM = W @ M (fp32 accum) -> fp16 fragments ----------------
// Same fragment layout as prep 1: lane holds WM[ft*16+(l&15)][kc*32+(l>>4)*8 + j].
__global__ __launch_bounds__(256)
void prep_wm_f16(const float* __restrict__ Ap, const float* __restrict__ Bp,
                 const float* __restrict__ Cp, const float* __restrict__ Wp,
                 _Float16* __restrict__ wsWM)
{
    const int row = blockIdx.x * 256 + threadIdx.x;   // 0 .. M_ROWS-1
    const int l   = row & 63;
    const int ft  = (row >> 6) & 15;
    const int kc  = row >> 10;
    const int f   = ft * 16 + (l & 15);
    const int k0  = kc * 32 + ((l >> 4) << 3);

    const float* src;
    int e0;
    if (k0 < 256)      { src = Ap; e0 = k0; }
    else if (k0 < 512) { src = Bp; e0 = k0 - 256; }
    else               { src = Cp; e0 = k0 - 512; }

    const float4* S4 = reinterpret_cast<const float4*>(src);
    const float*  Wr = Wp + f * 256;
    const int e4 = e0 >> 2;

    float acc[8];
    #pragma unroll
    for (int j = 0; j < 8; ++j) acc[j] = 0.f;

    for (int g = 0; g < 256; g += 4) {
        const float4 w4 = *reinterpret_cast<const float4*>(Wr + g);
        #pragma unroll
        for (int u = 0; u < 4; ++u) {
            const float wv = (u == 0) ? w4.x : (u == 1) ? w4.y : (u == 2) ? w4.z : w4.w;
            const float4 vA = S4[(g + u) * 64 + e4];
            const float4 vB = S4[(g + u) * 64 + e4 + 1];
            acc[0] += wv * vA.x; acc[1] += wv * vA.y; acc[2] += wv * vA.z; acc[3] += wv * vA.w;
            acc[4] += wv * vB.x; acc[5] += wv * vB.y; acc[6] += wv * vB.z; acc[7] += wv * vB.w;
        }
    }
    half8 v;
    #pragma unroll
    for (int j = 0; j < 8; ++j) v[j] = (_Float16)acc[j];
    *reinterpret_cast<half8*>(wsWM + (size_t)row * 8) = v;
}

// ---------------- fused main kernel (fold): 512 threads, ONE barrier ----------------
__global__ __launch_bounds__(512, 4)
void fused_fold_f16(const float* __restrict__ Xp, const float* __restrict__ Jp,
                    const _Float16* __restrict__ wsM, const _Float16* __restrict__ wsWM,
                    float* __restrict__ outp)
{
    __shared__ __align__(16) _Float16 lds[48 * ZLD];   // 74,496 B -> 2 blocks/CU

    const int t  = threadIdx.x;
    const int s0 = blockIdx.x * NT;
    const int b  = s0 >> 11;
    const int c0 = s0 & (Cdim - 1);

    // ---- phase 1: basis + abc -> Zt (fp16), e-quad per thread, 2 sites each ----
    {
        const int equad = t & 63;
        const int sq    = t >> 6;
        const int e0    = equad * 4;
        #pragma unroll
        for (int ss = 0; ss < 2; ++ss) {
            const int s = sq * 2 + ss;
            const long site = (long)(b * Cdim + c0 + s);
            const float4* X4 = reinterpret_cast<const float4*>(Xp) + site * 192 + equad * 3;
            const float4* J4 = reinterpret_cast<const float4*>(Jp) + site * 192 + equad * 3;
            const float4 xA = X4[0], xB = X4[1], xC = X4[2];
            const float4 jA = J4[0], jB = J4[1], jC = J4[2];
            const float xf[12] = {xA.x,xA.y,xA.z,xA.w, xB.x,xB.y,xB.z,xB.w, xC.x,xC.y,xC.z,xC.w};
            const float jf[12] = {jA.x,jA.y,jA.z,jA.w, jB.x,jB.y,jB.z,jB.w, jC.x,jC.y,jC.z,jC.w};

            half4 za[3], zb[3], zc[3];
            #pragma unroll
            for (int ee = 0; ee < 4; ++ee) {
                float a[3], bb[3], cc[3];
                basis_abc(xf[3*ee], xf[3*ee+1], xf[3*ee+2],
                          jf[3*ee], jf[3*ee+1], jf[3*ee+2], a, bb, cc);
                #pragma unroll
                for (int i = 0; i < 3; ++i) {
                    za[i][ee] = (_Float16)a[i];
                    zb[i][ee] = (_Float16)bb[i];
                    zc[i][ee] = (_Float16)cc[i];
                }
            }
            #pragma unroll
            for (int i = 0; i < 3; ++i) {
                _Float16* rowp = &lds[(i * NT + s) * ZLD];
                *reinterpret_cast<half4*>(rowp +       e0) = za[i];
                *reinterpret_cast<half4*>(rowp + 256 + e0) = zb[i];
                *reinterpret_cast<half4*>(rowp + 512 + e0) = zc[i];
            }
        }
    }
    __syncthreads();   // the ONLY barrier

    const int wid = t >> 6;
    const int l   = t & 63;
    const int lr  = l & 15;
    const int lk  = (l >> 4) * 8;

    // ---- single GEMM phase: Y = M.Z and D = (WM).Z from the same zf ----
    f32x4 Yacc[2][3], Dacc[2][3];
    #pragma unroll
    for (int q = 0; q < 2; ++q)
        #pragma unroll
        for (int nt = 0; nt < 3; ++nt) {
            Yacc[q][nt] = f32x4{0.f, 0.f, 0.f, 0.f};
            Dacc[q][nt] = f32x4{0.f, 0.f, 0.f, 0.f};
        }

    const half8* Mf = reinterpret_cast<const half8*>(wsM);
    const half8* Gf = reinterpret_cast<const half8*>(wsWM);
    for (int kc = 0; kc < KC1; ++kc) {
        half8 af[2], gf[2];
        #pragma unroll
        for (int q = 0; q < 2; ++q) {
            af[q] = Mf[(kc * 16 + wid * 2 + q) * 64 + l];
            gf[q] = Gf[(kc * 16 + wid * 2 + q) * 64 + l];
        }
        half8 zf[3];
        #pragma unroll
        for (int nt = 0; nt < 3; ++nt)
            zf[nt] = *reinterpret_cast<const half8*>(&lds[(nt * NT + lr) * ZLD + kc * 32 + lk]);
        #pragma unroll
        for (int q = 0; q < 2; ++q)
            #pragma unroll
            for (int nt = 0; nt < 3; ++nt) {
                Yacc[q][nt] = __builtin_amdgcn_mfma_f32_16x16x32_f16(af[q], zf[nt], Yacc[q][nt], 0, 0, 0);
                Dacc[q][nt] = __builtin_amdgcn_mfma_f32_16x16x32_f16(gf[q], zf[nt], Dacc[q][nt], 0, 0, 0);
            }
    }

    // ---- epilogue: leaky projection (np-exact op order), direct stores ----
    #pragma unroll
    for (int q = 0; q < 2; ++q) {
        const int fbase = (wid * 2 + q) * 16 + (l >> 4) * 4;
        #pragma unroll
        for (int r = 0; r < 4; ++r) {
#pragma clang fp contract(off)
            const float x0 = Yacc[q][0][r], x1 = Yacc[q][1][r], x2 = Yacc[q][2][r];
            const float d0 = Dacc[q][0][r], d1 = Dacc[q][1][r], d2 = Dacc[q][2][r];
            const float dot = (x0*d0 + x1*d1) + x2*d2;
            const float dns = (d0*d0 + d1*d1) + d2*d2;
            const float sc  = dot / (dns + EPSf);
            const bool  pos = (dot >= 0.f);
            const int f = fbase + r;
            const long obase = ((long)(b * Fdim + f) * 3) * Cdim + c0 + lr;
            const float c0v = pos ? x0 : (x0 - sc*d0);
            const float c1v = pos ? x1 : (x1 - sc*d1);
            const float c2v = pos ? x2 : (x2 - sc*d2);
            outp[obase + 0 * Cdim] = 0.2f*x0 + 0.8f*c0v;
            outp[obase + 1 * Cdim] = 0.2f*x1 + 0.8f*c1v;
            outp[obase + 2 * Cdim] = 0.2f*x2 + 0.8f*c2v;
        }
    }
}

// ---------------- r9 kernel (fallback if ws fits only M+W fragments) ----------------
__global__ __launch_bounds__(512, 4)
void fused_mfma_f16(const float* __restrict__ Xp, const float* __restrict__ Jp,
                    const _Float16* __restrict__ wsM, const _Float16* __restrict__ wsW,
                    float* __restrict__ outp)
{
    __shared__ __align__(16) _Float16 lds[48 * ZLD];

    const int t  = threadIdx.x;
    const int s0 = blockIdx.x * NT;
    const int b  = s0 >> 11;
    const int c0 = s0 & (Cdim - 1);

    {
        const int equad = t & 63;
        const int sq    = t >> 6;
        const int e0    = equad * 4;
        #pragma unroll
        for (int ss = 0; ss < 2; ++ss) {
            const int s = sq * 2 + ss;
            const long site = (long)(b * Cdim + c0 + s);
            const float4* X4 = reinterpret_cast<const float4*>(Xp) + site * 192 + equad * 3;
            const float4* J4 = reinterpret_cast<const float4*>(Jp) + site * 192 + equad * 3;
            const float4 xA = X4[0], xB = X4[1], xC = X4[2];
            const float4 jA = J4[0], jB = J4[1], jC = J4[2];
            const float xf[12] = {xA.x,xA.y,xA.z,xA.w, xB.x,xB.y,xB.z,xB.w, xC.x,xC.y,xC.z,xC.w};
            const float jf[12] = {jA.x,jA.y,jA.z,jA.w, jB.x,jB.y,jB.z,jB.w, jC.x,jC.y,jC.z,jC.w};
            half4 za[3], zb[3], zc[3];
            #pragma unroll
            for (int ee = 0; ee < 4; ++ee) {
                float a[3], bb[3], cc[3];
                basis_abc(xf[3*ee], xf[3*ee+1], xf[3*ee+2],
                          jf[3*ee], jf[3*ee+1], jf[3*ee+2], a, bb, cc);
                #pragma unroll
                for (int i = 0; i < 3; ++i) {
                    za[i][ee] = (_Float16)a[i];
                    zb[i][ee] = (_Float16)bb[i];
                    zc[i][ee] = (_Float16)cc[i];
                }
            }
            #pragma unroll
            for (int i = 0; i < 3; ++i) {
                _Float16* rowp = &lds[(i * NT + s) * ZLD];
                *reinterpret_cast<half4*>(rowp +       e0) = za[i];
                *reinterpret_cast<half4*>(rowp + 256 + e0) = zb[i];
                *reinterpret_cast<half4*>(rowp + 512 + e0) = zc[i];
            }
        }
    }
    __syncthreads();

    const int wid = t >> 6;
    const int l   = t & 63;
    const int lr  = l & 15;
    const int lk  = (l >> 4) * 8;

    f32x4 Yacc[2][3];
    #pragma unroll
    for (int q = 0; q < 2; ++q)
        #pragma unroll
        for (int nt = 0; nt < 3; ++nt)
            Yacc[q][nt] = f32x4{0.f, 0.f, 0.f, 0.f};

    const half8* Mf = reinterpret_cast<const half8*>(wsM);
    for (int kc = 0; kc < KC1; ++kc) {
        half8 af[2];
        #pragma unroll
        for (int q = 0; q < 2; ++q)
            af[q] = Mf[(kc * 16 + wid * 2 + q) * 64 + l];
        half8 zf[3];
        #pragma unroll
        for (int nt = 0; nt < 3; ++nt)
            zf[nt] = *reinterpret_cast<const half8*>(&lds[(nt * NT + lr) * ZLD + kc * 32 + lk]);
        #pragma unroll
        for (int q = 0; q < 2; ++q)
            #pragma unroll
            for (int nt = 0; nt < 3; ++nt)
                Yacc[q][nt] = __builtin_amdgcn_mfma_f32_16x16x32_f16(af[q], zf[nt], Yacc[q][nt], 0, 0, 0);
    }
    __syncthreads();

    #pragma unroll
    for (int q = 0; q < 2; ++q) {
        const int row = (wid * 2 + q) * 16 + (l >> 4) * 4;
        #pragma unroll
        for (int nt = 0; nt < 3; ++nt) {
            const int col = nt * NT + lr;
            half4 v = { (_Float16)Yacc[q][nt][0], (_Float16)Yacc[q][nt][1],
                        (_Float16)Yacc[q][nt][2], (_Float16)Yacc[q][nt][3] };
            *reinterpret_cast<half4*>(&lds[col * YLD + row]) = v;
        }
    }
    __syncthreads();

    f32x4 Dacc[2][3];
    #pragma unroll
    for (int q = 0; q < 2; ++q)
        #pragma unroll
        for (int nt = 0; nt < 3; ++nt)
            Dacc[q][nt] = f32x4{0.f, 0.f, 0.f, 0.f};

    const half8* Wf = reinterpret_cast<const half8*>(wsW);
    for (int kc = 0; kc < KC2; ++kc) {
        half8 af[2];
        #pragma unroll
        for (int q = 0; q < 2; ++q)
            af[q] = Wf[(kc * 16 + wid * 2 + q) * 64 + l];
        half8 yf[3];
        #pragma unroll
        for (int nt = 0; nt < 3; ++nt)
            yf[nt] = *reinterpret_cast<const half8*>(&lds[(nt * NT + lr) * YLD + kc * 32 + lk]);
        #pragma unroll
        for (int q = 0; q < 2; ++q)
            #pragma unroll
            for (int nt = 0; nt < 3; ++nt)
                Dacc[q][nt] = __builtin_amdgcn_mfma_f32_16x16x32_f16(af[q], yf[nt], Dacc[q][nt], 0, 0, 0);
    }

    #pragma unroll
    for (int q = 0; q < 2; ++q) {
        const int fbase = (wid * 2 + q) * 16 + (l >> 4) * 4;
        #pragma unroll
        for (int r = 0; r < 4; ++r) {
#pragma clang fp contract(off)
            const float x0 = Yacc[q][0][r], x1 = Yacc[q][1][r], x2 = Yacc[q][2][r];
            const float d0 = Dacc[q][0][r], d1 = Dacc[q][1][r], d2 = Dacc[q][2][r];
            const float dot = (x0*d0 + x1*d1) + x2*d2;
            const float dns = (d0*d0 + d1*d1) + d2*d2;
            const float sc  = dot / (dns + EPSf);
            const bool  pos = (dot >= 0.f);
            const int f = fbase + r;
            const long obase = ((long)(b * Fdim + f) * 3) * Cdim + c0 + lr;
            const float c0v = pos ? x0 : (x0 - sc*d0);
            const float c1v = pos ? x1 : (x1 - sc*d1);
            const float c2v = pos ? x2 : (x2 - sc*d2);
            outp[obase + 0 * Cdim] = 0.2f*x0 + 0.8f*c0v;
            outp[obase + 1 * Cdim] = 0.2f*x1 + 0.8f*c1v;
            outp[obase + 2 * Cdim] = 0.2f*x2 + 0.8f*c2v;
        }
    }
}

// ---------------- fp32 fallback (last resort) ----------------
__device__ __forceinline__ float comp(const float4& v, int k) {
    return k == 0 ? v.x : k == 1 ? v.y : k == 2 ? v.z : v.w;
}

__global__ __launch_bounds__(256)
void fused_cl_lrelu_fp32(const float* __restrict__ Xp, const float* __restrict__ Jp,
                         const float* __restrict__ Ap, const float* __restrict__ Bp,
                         const float* __restrict__ Cp, const float* __restrict__ Wp,
                         float* __restrict__ outp)
{
    __shared__ float4 sabc[4 * Edim * 3];
    __shared__ float  ylds[4 * 3][Fdim];

    const int t   = threadIdx.x;
    const int s0  = blockIdx.x * 4;
    const int b   = s0 / Cdim;
    const int c0  = s0 % Cdim;

    #pragma unroll
    for (int r = 0; r < 4; ++r) {
        const int e  = t;
        const int idx = ((b * Cdim + c0 + r) * Edim + e) * 3;
        float a[3], bb[3], cc[3];
        basis_abc(Xp[idx], Xp[idx+1], Xp[idx+2], Jp[idx], Jp[idx+1], Jp[idx+2], a, bb, cc);
        const int base = (r * Edim + e) * 3;
        sabc[base + 0] = make_float4(a[0], a[1], a[2], bb[0]);
        sabc[base + 1] = make_float4(bb[1], bb[2], cc[0], cc[1]);
        sabc[base + 2] = make_float4(cc[2], 0.f, 0.f, 0.f);
    }
    __syncthreads();

    const int fl = t & 63;
    const int cg = t >> 6;
    float Y[4][3];
    #pragma unroll
    for (int q = 0; q < 4; ++q) Y[q][0] = Y[q][1] = Y[q][2] = 0.f;

    const float4* A4 = reinterpret_cast<const float4*>(Ap);
    const float4* B4 = reinterpret_cast<const float4*>(Bp);
    const float4* C4 = reinterpret_cast<const float4*>(Cp);
    for (int e4 = 0; e4 < Edim / 4; ++e4) {
        float4 wa[4], wb[4], wc[4];
        #pragma unroll
        for (int q = 0; q < 4; ++q) {
            const int f = q * 64 + fl;
            wa[q] = A4[f * (Edim/4) + e4];
            wb[q] = B4[f * (Edim/4) + e4];
            wc[q] = C4[f * (Edim/4) + e4];
        }
        #pragma unroll
        for (int k = 0; k < 4; ++k) {
            const int e = e4 * 4 + k;
            const float4 p0 = sabc[(cg * Edim + e) * 3 + 0];
            const float4 p1 = sabc[(cg * Edim + e) * 3 + 1];
            const float4 p2 = sabc[(cg * Edim + e) * 3 + 2];
            #pragma unroll
            for (int q = 0; q < 4; ++q) {
                const float Af = comp(wa[q], k), Bf = comp(wb[q], k), Cf = comp(wc[q], k);
                Y[q][0] += Af * p0.x + Bf * p0.w + Cf * p1.z;
                Y[q][1] += Af * p0.y + Bf * p1.x + Cf * p1.w;
                Y[q][2] += Af * p0.z + Bf * p1.y + Cf * p2.x;
            }
        }
    }
    #pragma unroll
    for (int q = 0; q < 4; ++q) {
        const int f = q * 64 + fl;
        ylds[cg * 3 + 0][f] = Y[q][0];
        ylds[cg * 3 + 1][f] = Y[q][1];
        ylds[cg * 3 + 2][f] = Y[q][2];
    }
    __syncthreads();

    float D[4][3];
    #pragma unroll
    for (int q = 0; q < 4; ++q) D[q][0] = D[q][1] = D[q][2] = 0.f;
    const float4* W4 = reinterpret_cast<const float4*>(Wp);
    for (int g4 = 0; g4 < Fdim / 4; ++g4) {
        float4 ww[4];
        #pragma unroll
        for (int q = 0; q < 4; ++q) ww[q] = W4[(q * 64 + fl) * (Fdim/4) + g4];
        const float4 y0 = *reinterpret_cast<const float4*>(&ylds[cg * 3 + 0][g4 * 4]);
        const float4 y1 = *reinterpret_cast<const float4*>(&ylds[cg * 3 + 1][g4 * 4]);
        const float4 y2 = *reinterpret_cast<const float4*>(&ylds[cg * 3 + 2][g4 * 4]);
        #pragma unroll
        for (int k = 0; k < 4; ++k) {
            #pragma unroll
            for (int q = 0; q < 4; ++q) {
                const float Wv = comp(ww[q], k);
                D[q][0] += Wv * comp(y0, k);
                D[q][1] += Wv * comp(y1, k);
                D[q][2] += Wv * comp(y2, k);
            }
        }
    }

    float* outl = reinterpret_cast<float*>(sabc);
    #pragma unroll
    for (int q = 0; q < 4; ++q) {
        const int f = q * 64 + fl;
        const float dot = (Y[q][0]*D[q][0] + Y[q][1]*D[q][1]) + Y[q][2]*D[q][2];
        const float dns = (D[q][0]*D[q][0] + D[q][1]*D[q][1]) + D[q][2]*D[q][2];
        const float s   = dot / (dns + EPSf);
        const bool  pos = (dot >= 0.f);
        #pragma unroll
        for (int i = 0; i < 3; ++i) {
            const float x = Y[q][i], d = D[q][i];
            outl[(f * 3 + i) * 4 + cg] = 0.2f*x + 0.8f*(pos ? x : x - s*d);
        }
    }
    __syncthreads();
    const float4* o4 = reinterpret_cast<const float4*>(outl);
    float4* O4 = reinterpret_cast<float4*>(outp);
    const int c4 = c0 >> 2;
    #pragma unroll
    for (int i = 0; i < 3; ++i)
        O4[((b * Fdim + t) * 3 + i) * (Cdim / 4) + c4] = o4[t * 3 + i];
}

extern "C" void kernel_launch(void* const* d_in, const int* in_sizes, int n_in,
                              void* d_out, int out_size, void* d_ws, size_t ws_size,
                              hipStream_t stream) {
    const float* X  = (const float*)d_in[0];
    const float* J  = (const float*)d_in[1];
    const float* A  = (const float*)d_in[2];
    const float* Bw = (const float*)d_in[3];
    const float* Cw = (const float*)d_in[4];
    const float* W  = (const float*)d_in[5];
    float* out = (float*)d_out;

    constexpr size_t NEED_BASE = (size_t)(M_ROWS + W_ROWS) * 8 * sizeof(_Float16); // 512 KiB
    constexpr size_t NEED_FOLD = NEED_BASE + (size_t)M_ROWS * 8 * sizeof(_Float16); // 896 KiB

    _Float16* wsM  = (_Float16*)d_ws;
    _Float16* wsW  = wsM + (size_t)M_ROWS * 8;
    _Float16* wsWM = wsM + (size_t)(M_ROWS + W_ROWS) * 8;

    if (ws_size >= NEED_FOLD) {
        prep_weights_f16<<<(M_ROWS + W_ROWS) / 256, 256, 0, stream>>>(A, Bw, Cw, W, wsM);
        prep_wm_f16<<<M_ROWS / 256, 256, 0, stream>>>(A, Bw, Cw, W, wsWM);
        fused_fold_f16<<<Bdim * Cdim / NT, 512, 0, stream>>>(X, J, wsM, wsWM, out);
    } else if (ws_size >= NEED_BASE) {
        prep_weights_f16<<<(M_ROWS + W_ROWS) / 256, 256, 0, stream>>>(A, Bw, Cw, W, wsM);
        fused_mfma_f16<<<Bdim * Cdim / NT, 512, 0, stream>>>(X, J, wsM, wsW, out);
    } else {
        fused_cl_lrelu_fp32<<<Bdim * Cdim / 4, 256, 0, stream>>>(X, J, A, Bw, Cw, W, out);
    }
}

// Round 11
// 57.033 us; speedup vs baseline: 1.6427x; 1.6427x over previous
//
#include <hip/hip_runtime.h>

// ComplexLinearAndLeakyReLU — round 11: r9 structure + fragment-ordered LDS.
// Z and Yt stored in MFMA fragment order -> all LDS reads/writes are contiguous
// (conflict-free). Phase 1: thread = (site, e-octet), writes full half8 fragments.
// c[1] == 0 analytically -> skip c-part MFMA for n-tile 1 (kc>=16).
// Math identical to round 9 (fp16 MFMA, algebraic basis, np-exact epilogue).

constexpr float EPSf  = 1e-6f;
constexpr int Bdim = 8, Cdim = 2048, Edim = 256, Fdim = 256;
constexpr int NT  = 16;          // sites per block
constexpr int KC1 = 24;          // GEMM1 K chunks of 32 (K=768)
constexpr int KC2 = 8;           // GEMM2 K chunks of 32 (K=256)
constexpr int M_ROWS = KC1 * 16 * 64;   // fragment rows of M=[A|Bw|Cw]
constexpr int W_ROWS = KC2 * 16 * 64;   // fragment rows of W

typedef __attribute__((ext_vector_type(8))) _Float16 half8;
typedef __attribute__((ext_vector_type(4))) _Float16 half4;
typedef __attribute__((ext_vector_type(4))) float    f32x4;

// ---- basis + abc via orthonormal-column identity (round 9, validated) ----
__device__ __forceinline__ void basis_abc(float Xx, float Xy, float Xz,
                                          float Jx, float Jy, float Jz,
                                          float* a, float* bb, float* cc)
{
    const float jn  = sqrtf(Jx*Jx + Jy*Jy + Jz*Jz) + EPSf;
    const float rj  = __builtin_amdgcn_rcpf(jn);
    const float nJz = Jz * rj;
    const float h   = (Jx*Jx + Jy*Jy) * (rj * rj);
    const float Uz  = -h * __builtin_amdgcn_rcpf(nJz + EPSf);
    const float un  = sqrtf(h + Uz*Uz) + EPSf;
    const float mx  = Uz * __builtin_amdgcn_rcpf(un);
    const float mz  = nJz;
    const float t   = mx*Xx + mz*Xz;
    a[0]  = Xx - mx*t;   a[1]  = Xy;            a[2]  = Xz - mz*t;
    bb[0] = mz*Xy;       bb[1] = mx*Xz - mz*Xx; bb[2] = -(mx*Xy);
    cc[0] = mx*t;        cc[1] = 0.f;           cc[2] = mz*t;
}

// ---------------- weight prep: fp32 -> fp16 in MFMA A-fragment order ----------------
__global__ __launch_bounds__(256)
void prep_weights_f16(const float* __restrict__ Ap, const float* __restrict__ Bp,
                      const float* __restrict__ Cp, const float* __restrict__ Wp,
                      _Float16* __restrict__ ws)
{
    const int tid = blockIdx.x * 256 + threadIdx.x;
    const bool isW = tid >= M_ROWS;
    const int row = isW ? tid - M_ROWS : tid;
    const int l   = row & 63;
    const int ft  = (row >> 6) & 15;
    const int kc  = row >> 10;
    const int f   = ft * 16 + (l & 15);
    const int k0  = kc * 32 + ((l >> 4) << 3);

    const float* src;
    int e0;
    if (isW)            { src = Wp; e0 = k0; }
    else if (k0 < 256)  { src = Ap; e0 = k0; }
    else if (k0 < 512)  { src = Bp; e0 = k0 - 256; }
    else                { src = Cp; e0 = k0 - 512; }

    const float* p = src + f * 256 + e0;
    half8 v;
    #pragma unroll
    for (int j = 0; j < 8; ++j) v[j] = (_Float16)p[j];

    _Float16* dst = ws + (isW ? (size_t)M_ROWS * 8 : 0);
    *reinterpret_cast<half8*>(dst + (size_t)row * 8) = v;
}

// ---------------- fused main kernel: 512 threads = 8 waves ----------------
// LDS: Z in fragment order: Zf[(kc*3 + nt)*64 + lane] (half8). 72 KiB -> 2 blocks/CU.
// After GEMM1, the front 12 KiB region is re-used in the same order for Yt.
__global__ __launch_bounds__(512, 4)
void fused_mfma_f16(const float* __restrict__ Xp, const float* __restrict__ Jp,
                    const _Float16* __restrict__ wsM, const _Float16* __restrict__ wsW,
                    float* __restrict__ outp)
{
    __shared__ __align__(16) _Float16 lds[KC1 * 3 * 512];   // 73,728 B

    const int t  = threadIdx.x;
    const int s0 = blockIdx.x * NT;
    const int b  = s0 >> 11;
    const int c0 = s0 & (Cdim - 1);

    // ---- phase 1: thread = (site s, e-octet ep); writes full half8 fragments ----
    {
        const int s  = t & 15;
        const int ep = t >> 4;                 // 0..31, covers e = 8*ep .. 8*ep+7
        const long site = (long)(b * Cdim + c0 + s);
        const float4* X4 = reinterpret_cast<const float4*>(Xp) + site * 192 + ep * 6;
        const float4* J4 = reinterpret_cast<const float4*>(Jp) + site * 192 + ep * 6;

        float xf[24], jf[24];
        #pragma unroll
        for (int u = 0; u < 6; ++u) {
            const float4 xv = X4[u];
            const float4 jv = J4[u];
            xf[4*u+0] = xv.x; xf[4*u+1] = xv.y; xf[4*u+2] = xv.z; xf[4*u+3] = xv.w;
            jf[4*u+0] = jv.x; jf[4*u+1] = jv.y; jf[4*u+2] = jv.z; jf[4*u+3] = jv.w;
        }

        half8 za8[3], zb8[3], zc8[3];
        #pragma unroll
        for (int pt = 0; pt < 8; ++pt) {
            float a[3], bb[3], cc[3];
            basis_abc(xf[3*pt], xf[3*pt+1], xf[3*pt+2],
                      jf[3*pt], jf[3*pt+1], jf[3*pt+2], a, bb, cc);
            #pragma unroll
            for (int i = 0; i < 3; ++i) {
                za8[i][pt] = (_Float16)a[i];
                zb8[i][pt] = (_Float16)bb[i];
                zc8[i][pt] = (_Float16)cc[i];
            }
        }

        // fragment: kc = m*8 + (ep>>2); lane slot = (ep&3)*16 + s; j = e&7 = 0..7
        half8* Zf = reinterpret_cast<half8*>(lds);
        const int kcb  = ep >> 2;
        const int slot = (ep & 3) * 16 + s;
        #pragma unroll
        for (int i = 0; i < 3; ++i) {
            Zf[((kcb     ) * 3 + i) * 64 + slot] = za8[i];   // m=0 (a -> A)
            Zf[((kcb +  8) * 3 + i) * 64 + slot] = zb8[i];   // m=1 (b -> Bw)
            if (i != 1)
                Zf[((kcb + 16) * 3 + i) * 64 + slot] = zc8[i]; // m=2 (c -> Cw); c[1]==0 skipped
        }
    }
    __syncthreads();

    const int wid = t >> 6;          // wave owns f-tiles wid*2, wid*2+1
    const int l   = t & 63;
    const int lr  = l & 15;
    const int hi  = l >> 4;

    // ---- phase 2: GEMM1 over K=768; contiguous fragment reads ----
    f32x4 Yacc[2][3];
    #pragma unroll
    for (int q = 0; q < 2; ++q)
        #pragma unroll
        for (int nt = 0; nt < 3; ++nt)
            Yacc[q][nt] = f32x4{0.f, 0.f, 0.f, 0.f};

    const half8* Mf = reinterpret_cast<const half8*>(wsM);
    const half8* Zf = reinterpret_cast<const half8*>(lds);

    for (int kc = 0; kc < 16; ++kc) {           // a- and b-parts: all 3 n-tiles
        half8 af[2];
        #pragma unroll
        for (int q = 0; q < 2; ++q)
            af[q] = Mf[(kc * 16 + wid * 2 + q) * 64 + l];
        half8 zf[3];
        #pragma unroll
        for (int nt = 0; nt < 3; ++nt)
            zf[nt] = Zf[(kc * 3 + nt) * 64 + l];
        #pragma unroll
        for (int q = 0; q < 2; ++q)
            #pragma unroll
            for (int nt = 0; nt < 3; ++nt)
                Yacc[q][nt] = __builtin_amdgcn_mfma_f32_16x16x32_f16(af[q], zf[nt], Yacc[q][nt], 0, 0, 0);
    }
    for (int kc = 16; kc < KC1; ++kc) {         // c-part: n-tile 1 is identically zero
        half8 af[2];
        #pragma unroll
        for (int q = 0; q < 2; ++q)
            af[q] = Mf[(kc * 16 + wid * 2 + q) * 64 + l];
        const half8 zf0 = Zf[(kc * 3 + 0) * 64 + l];
        const half8 zf2 = Zf[(kc * 3 + 2) * 64 + l];
        #pragma unroll
        for (int q = 0; q < 2; ++q) {
            Yacc[q][0] = __builtin_amdgcn_mfma_f32_16x16x32_f16(af[q], zf0, Yacc[q][0], 0, 0, 0);
            Yacc[q][2] = __builtin_amdgcn_mfma_f32_16x16x32_f16(af[q], zf2, Yacc[q][2], 0, 0, 0);
        }
    }
    __syncthreads();   // all Z reads done; front region re-used for Yt

    // ---- stage Y as fp16 fragments: Yt[(kc2*3+nt)*64 + slot] ----
    #pragma unroll
    for (int q = 0; q < 2; ++q) {
        const int f0  = (wid * 2 + q) * 16 + hi * 4;   // g (=f) of reg 0
        const int kc2 = f0 >> 5;
        const int sub = (f0 >> 3) & 3;
        const int j0  = f0 & 7;                        // 0 or 4
        #pragma unroll
        for (int nt = 0; nt < 3; ++nt) {
            half4 v = { (_Float16)Yacc[q][nt][0], (_Float16)Yacc[q][nt][1],
                        (_Float16)Yacc[q][nt][2], (_Float16)Yacc[q][nt][3] };
            const int idx = ((kc2 * 3 + nt) * 64 + sub * 16 + lr) * 8 + j0;
            *reinterpret_cast<half4*>(&lds[idx]) = v;
        }
    }
    __syncthreads();

    // ---- phase 3: GEMM2 over K=256; contiguous fragment reads ----
    f32x4 Dacc[2][3];
    #pragma unroll
    for (int q = 0; q < 2; ++q)
        #pragma unroll
        for (int nt = 0; nt < 3; ++nt)
            Dacc[q][nt] = f32x4{0.f, 0.f, 0.f, 0.f};

    const half8* Wf = reinterpret_cast<const half8*>(wsW);
    const half8* Yf = reinterpret_cast<const half8*>(lds);
    for (int kc = 0; kc < KC2; ++kc) {
        half8 wf[2];
        #pragma unroll
        for (int q = 0; q < 2; ++q)
            wf[q] = Wf[(kc * 16 + wid * 2 + q) * 64 + l];
        half8 yf[3];
        #pragma unroll
        for (int nt = 0; nt < 3; ++nt)
            yf[nt] = Yf[(kc * 3 + nt) * 64 + l];
        #pragma unroll
        for (int q = 0; q < 2; ++q)
            #pragma unroll
            for (int nt = 0; nt < 3; ++nt)
                Dacc[q][nt] = __builtin_amdgcn_mfma_f32_16x16x32_f16(wf[q], yf[nt], Dacc[q][nt], 0, 0, 0);
    }

    // ---- epilogue: leaky projection (np-exact op order), direct stores ----
    #pragma unroll
    for (int q = 0; q < 2; ++q) {
        const int fbase = (wid * 2 + q) * 16 + hi * 4;
        #pragma unroll
        for (int r = 0; r < 4; ++r) {
#pragma clang fp contract(off)
            const float x0 = Yacc[q][0][r], x1 = Yacc[q][1][r], x2 = Yacc[q][2][r];
            const float d0 = Dacc[q][0][r], d1 = Dacc[q][1][r], d2 = Dacc[q][2][r];
            const float dot = (x0*d0 + x1*d1) + x2*d2;
            const float dns = (d0*d0 + d1*d1) + d2*d2;
            const float sc  = dot / (dns + EPSf);
            const bool  pos = (dot >= 0.f);
            const int f = fbase + r;
            const long obase = ((long)(b * Fdim + f) * 3) * Cdim + c0 + lr;
            const float c0v = pos ? x0 : (x0 - sc*d0);
            const float c1v = pos ? x1 : (x1 - sc*d1);
            const float c2v = pos ? x2 : (x2 - sc*d2);
            outp[obase + 0 * Cdim] = 0.2f*x0 + 0.8f*c0v;
            outp[obase + 1 * Cdim] = 0.2f*x1 + 0.8f*c1v;
            outp[obase + 2 * Cdim] = 0.2f*x2 + 0.8f*c2v;
        }
    }
}

// ---------------- fp32 fallback if ws too small ----------------
__device__ __forceinline__ float comp(const float4& v, int k) {
    return k == 0 ? v.x : k == 1 ? v.y : k == 2 ? v.z : v.w;
}

__global__ __launch_bounds__(256)
void fused_cl_lrelu_fp32(const float* __restrict__ Xp, const float* __restrict__ Jp,
                         const float* __restrict__ Ap, const float* __restrict__ Bp,
                         const float* __restrict__ Cp, const float* __restrict__ Wp,
                         float* __restrict__ outp)
{
    __shared__ float4 sabc[4 * Edim * 3];
    __shared__ float  ylds[4 * 3][Fdim];

    const int t   = threadIdx.x;
    const int s0  = blockIdx.x * 4;
    const int b   = s0 / Cdim;
    const int c0  = s0 % Cdim;

    #pragma unroll
    for (int r = 0; r < 4; ++r) {
        const int e  = t;
        const int idx = ((b * Cdim + c0 + r) * Edim + e) * 3;
        float a[3], bb[3], cc[3];
        basis_abc(Xp[idx], Xp[idx+1], Xp[idx+2], Jp[idx], Jp[idx+1], Jp[idx+2], a, bb, cc);
        const int base = (r * Edim + e) * 3;
        sabc[base + 0] = make_float4(a[0], a[1], a[2], bb[0]);
        sabc[base + 1] = make_float4(bb[1], bb[2], cc[0], cc[1]);
        sabc[base + 2] = make_float4(cc[2], 0.f, 0.f, 0.f);
    }
    __syncthreads();

    const int fl = t & 63;
    const int cg = t >> 6;
    float Y[4][3];
    #pragma unroll
    for (int q = 0; q < 4; ++q) Y[q][0] = Y[q][1] = Y[q][2] = 0.f;

    const float4* A4 = reinterpret_cast<const float4*>(Ap);
    const float4* B4 = reinterpret_cast<const float4*>(Bp);
    const float4* C4 = reinterpret_cast<const float4*>(Cp);
    for (int e4 = 0; e4 < Edim / 4; ++e4) {
        float4 wa[4], wb[4], wc[4];
        #pragma unroll
        for (int q = 0; q < 4; ++q) {
            const int f = q * 64 + fl;
            wa[q] = A4[f * (Edim/4) + e4];
            wb[q] = B4[f * (Edim/4) + e4];
            wc[q] = C4[f * (Edim/4) + e4];
        }
        #pragma unroll
        for (int k = 0; k < 4; ++k) {
            const int e = e4 * 4 + k;
            const float4 p0 = sabc[(cg * Edim + e) * 3 + 0];
            const float4 p1 = sabc[(cg * Edim + e) * 3 + 1];
            const float4 p2 = sabc[(cg * Edim + e) * 3 + 2];
            #pragma unroll
            for (int q = 0; q < 4; ++q) {
                const float Af = comp(wa[q], k), Bf = comp(wb[q], k), Cf = comp(wc[q], k);
                Y[q][0] += Af * p0.x + Bf * p0.w + Cf * p1.z;
                Y[q][1] += Af * p0.y + Bf * p1.x + Cf * p1.w;
                Y[q][2] += Af * p0.z + Bf * p1.y + Cf * p2.x;
            }
        }
    }
    #pragma unroll
    for (int q = 0; q < 4; ++q) {
        const int f = q * 64 + fl;
        ylds[cg * 3 + 0][f] = Y[q][0];
        ylds[cg * 3 + 1][f] = Y[q][1];
        ylds[cg * 3 + 2][f] = Y[q][2];
    }
    __syncthreads();

    float D[4][3];
    #pragma unroll
    for (int q = 0; q < 4; ++q) D[q][0] = D[q][1] = D[q][2] = 0.f;
    const float4* W4 = reinterpret_cast<const float4*>(Wp);
    for (int g4 = 0; g4 < Fdim / 4; ++g4) {
        float4 ww[4];
        #pragma unroll
        for (int q = 0; q < 4; ++q) ww[q] = W4[(q * 64 + fl) * (Fdim/4) + g4];
        const float4 y0 = *reinterpret_cast<const float4*>(&ylds[cg * 3 + 0][g4 * 4]);
        const float4 y1 = *reinterpret_cast<const float4*>(&ylds[cg * 3 + 1][g4 * 4]);
        const float4 y2 = *reinterpret_cast<const float4*>(&ylds[cg * 3 + 2][g4 * 4]);
        #pragma unroll
        for (int k = 0; k < 4; ++k) {
            #pragma unroll
            for (int q = 0; q < 4; ++q) {
                const float Wv = comp(ww[q], k);
                D[q][0] += Wv * comp(y0, k);
                D[q][1] += Wv * comp(y1, k);
                D[q][2] += Wv * comp(y2, k);
            }
        }
    }

    float* outl = reinterpret_cast<float*>(sabc);
    #pragma unroll
    for (int q = 0; q < 4; ++q) {
        const int f = q * 64 + fl;
        const float dot = (Y[q][0]*D[q][0] + Y[q][1]*D[q][1]) + Y[q][2]*D[q][2];
        const float dns = (D[q][0]*D[q][0] + D[q][1]*D[q][1]) + D[q][2]*D[q][2];
        const float s   = dot / (dns + EPSf);
        const bool  pos = (dot >= 0.f);
        #pragma unroll
        for (int i = 0; i < 3; ++i) {
            const float x = Y[q][i], d = D[q][i];
            outl[(f * 3 + i) * 4 + cg] = 0.2f*x + 0.8f*(pos ? x : x - s*d);
        }
    }
    __syncthreads();
    const float4* o4 = reinterpret_cast<const float4*>(outl);
    float4* O4 = reinterpret_cast<float4*>(outp);
    const int c4 = c0 >> 2;
    #pragma unroll
    for (int i = 0; i < 3; ++i)
        O4[((b * Fdim + t) * 3 + i) * (Cdim / 4) + c4] = o4[t * 3 + i];
}

extern "C" void kernel_launch(void* const* d_in, const int* in_sizes, int n_in,
                              void* d_out, int out_size, void* d_ws, size_t ws_size,
                              hipStream_t stream) {
    const float* X  = (const float*)d_in[0];
    const float* J  = (const float*)d_in[1];
    const float* A  = (const float*)d_in[2];
    const float* Bw = (const float*)d_in[3];
    const float* Cw = (const float*)d_in[4];
    const float* W  = (const float*)d_in[5];
    float* out = (float*)d_out;

    constexpr size_t WS_NEED = (size_t)(M_ROWS + W_ROWS) * 8 * sizeof(_Float16);  // 512 KiB
    if (ws_size >= WS_NEED) {
        _Float16* wsM = (_Float16*)d_ws;
        _Float16* wsW = wsM + (size_t)M_ROWS * 8;
        prep_weights_f16<<<(M_ROWS + W_ROWS) / 256, 256, 0, stream>>>(A, Bw, Cw, W, wsM);
        fused_mfma_f16<<<Bdim * Cdim / NT, 512, 0, stream>>>(X, J, wsM, wsW, out);
    } else {
        fused_cl_lrelu_fp32<<<Bdim * Cdim / 4, 256, 0, stream>>>(X, J, A, Bw, Cw, W, out);
    }
}